// Round 7
// baseline (7390.352 us; speedup 1.0000x reference)
//
#include <hip/hip_runtime.h>

typedef _Float16 half8 __attribute__((ext_vector_type(8)));
typedef float f32x4 __attribute__((ext_vector_type(4)));

#define AGENT __HIP_MEMORY_SCOPE_AGENT

__device__ __forceinline__ float sigf(float x) { return 1.f / (1.f + __expf(-x)); }
__device__ __forceinline__ float tanhf_(float x) {
  float e = __expf(-2.f * fabsf(x));
  float t = (1.f - e) / (1.f + e);
  return copysignf(t, x);
}

// ---------------- workspace layout (bytes) ----------------
static const size_t O_WGT   = 0;                                  // 2 MB packed Whh f16
static const size_t O_XF16  = O_WGT   + (size_t)2*1024*1024;      // 4096x32 f16
static const size_t O_WIH0P = O_XF16  + 262144;                   // 2x1024x32 f16 (rows permuted)
static const size_t O_B0P   = O_WIH0P + 131072;                   // 2x1024 f32 (permuted)
static const size_t O_WIH1P = O_B0P   + 8192;                     // 2x1024x512 f16 (permuted)
static const size_t O_B1P   = O_WIH1P + 2097152;                  // 2x1024 f32
static const size_t O_W1F   = O_B1P   + 8192;                     // 1024x512 f16
static const size_t O_W2F   = O_W1F   + 1048576;                  // 512x1024 f16
static const size_t O_W3SF  = O_W2F   + 1048576;                  // 1024x512 f16 (W3a+W3b)
static const size_t O_P0    = O_W3SF  + 1048576;                  // 2x4096x1024 f32
static const size_t O_H0    = O_P0    + (size_t)32*1024*1024;     // 4096x512 f16
static const size_t O_P1    = O_H0    + 4194304;                  // 2x4096x1024 f32
static const size_t O_H1    = O_P1    + (size_t)32*1024*1024;     // 4096x512 f16
static const size_t O_M1    = O_H1    + 4194304;                  // 4096x1024 f16
static const size_t O_E     = O_M1    + 8388608;                  // 4096x512 f16
static const size_t O_S     = O_E     + 4194304;                  // 4096x1024 f32
static const size_t O_XG    = O_S     + (size_t)16*1024*1024;     // 8 KB tagged h-exchange
static const size_t WS_NEED = O_XG    + 8192;

// ---------------- pack recurrent weights into per-lane MFMA A-fragments ----------------
// Layout: wgt[layer][d][mt 0..63][kc 0..7][lane 0..63] half8.
// M-tile mt covers permuted rows: row m in tile -> unit = mt*4 + (m>>2), gate = m&3,
// original row = gate*256 + unit. A-frag (16x16x32 f16): lane holds
// A[m=lane&15][k = kc*32 + (lane>>4)*8 + j], j=0..7.
__global__ void pack_whh(const float* __restrict__ Whh0, const float* __restrict__ Whh1,
                         half8* __restrict__ wgt) {
  int flat = blockIdx.x * 256 + threadIdx.x;        // [0, 131072)
  int lane = flat & 63;
  int kc   = (flat >> 6) & 7;
  int mt   = (flat >> 9) & 63;
  int d    = (flat >> 15) & 1;
  int layer = flat >> 16;
  int m = lane & 15, q = lane >> 4;
  int ul = mt * 4 + (m >> 2), gate = m & 3;
  int grow = gate * 256 + ul;
  const float* src = (layer ? Whh1 : Whh0) + ((size_t)d * 1024 + grow) * 256 + kc * 32 + q * 8;
  half8 v;
#pragma unroll
  for (int j = 0; j < 8; ++j) v[j] = (_Float16)src[j];
  wgt[flat] = v;
}

// ---------------- pack everything else ----------------
__global__ void pack_misc(const float* __restrict__ v_r, const float* __restrict__ v_l,
                          const float* __restrict__ Wih0, const float* __restrict__ bih0,
                          const float* __restrict__ bhh0, const float* __restrict__ Wih1,
                          const float* __restrict__ bih1, const float* __restrict__ bhh1,
                          const float* __restrict__ W1, const float* __restrict__ W2,
                          const float* __restrict__ W3,
                          _Float16* __restrict__ xf16, _Float16* __restrict__ wih0p,
                          float* __restrict__ b0p, _Float16* __restrict__ wih1p,
                          float* __restrict__ b1p, _Float16* __restrict__ w1f,
                          _Float16* __restrict__ w2f, _Float16* __restrict__ w3sf) {
  int idx = blockIdx.x * 256 + threadIdx.x;
  if (idx < 131072) {                               // X f16 [4096][32], K padded 22->32
    int row = idx >> 5, k = idx & 31;
    float v = 0.f;
    if (k < 22) v = (row < 2048) ? v_r[row * 22 + k] : v_l[(row - 2048) * 22 + k];
    xf16[idx] = (_Float16)v;
    return;
  }
  idx -= 131072;
  if (idx < 65536) {                                // Wih0 permuted rows, K padded
    int d = idx >> 15, jp = (idx >> 5) & 1023, k = idx & 31;
    int u = jp >> 2, g = jp & 3, j = g * 256 + u;
    float v = (k < 22) ? Wih0[((size_t)d * 1024 + j) * 22 + k] : 0.f;
    wih0p[idx] = (_Float16)v;
    return;
  }
  idx -= 65536;
  if (idx < 2048) {                                 // bias0 permuted
    int d = idx >> 10, jp = idx & 1023;
    int u = jp >> 2, g = jp & 3, j = d * 1024 + g * 256 + u;
    b0p[idx] = bih0[j] + bhh0[j];
    return;
  }
  idx -= 2048;
  if (idx < 1048576) {                              // Wih1 permuted rows
    int d = idx >> 19, jp = (idx >> 9) & 1023, k = idx & 511;
    int u = jp >> 2, g = jp & 3;
    wih1p[idx] = (_Float16)Wih1[((size_t)d * 1024 + g * 256 + u) * 512 + k];
    return;
  }
  idx -= 1048576;
  if (idx < 2048) {                                 // bias1 permuted
    int d = idx >> 10, jp = idx & 1023;
    int u = jp >> 2, g = jp & 3, j = d * 1024 + g * 256 + u;
    b1p[idx] = bih1[j] + bhh1[j];
    return;
  }
  idx -= 2048;
  if (idx < 524288) { w1f[idx] = (_Float16)W1[idx]; return; }
  idx -= 524288;
  if (idx < 524288) { w2f[idx] = (_Float16)W2[idx]; return; }
  idx -= 524288;
  if (idx < 524288) {                               // W3s = W3[:, :512] + W3[:, 512:]
    int j = idx >> 9, k = idx & 511;
    w3sf[idx] = (_Float16)(W3[(size_t)j * 1024 + k] + W3[(size_t)j * 1024 + 512 + k]);
    return;
  }
}

// ---------------- generic NT GEMM: C[M,N] = A[M,K]f16 * B[N,K]f16 (+bias)(+relu) ----------------
__global__ __launch_bounds__(256) void gemm_nt(
    const _Float16* __restrict__ A, const _Float16* __restrict__ B,
    const float* __restrict__ bias, void* __restrict__ Cout,
    int N, int K, int do_relu, int f16out, int hasbias) {
  __shared__ _Float16 as[64][40];
  __shared__ _Float16 bs[64][40];
  const int tid = threadIdx.x;
  const int w = tid >> 6, lane = tid & 63, q = lane >> 4, m15 = lane & 15;
  const int bm = blockIdx.x * 64, bn = blockIdx.y * 64;
  const int srow = tid >> 2, spart = tid & 3;
  f32x4 acc[4] = {};
  for (int k0 = 0; k0 < K; k0 += 32) {
    if (k0) __syncthreads();
    *(half8*)&as[srow][spart * 8] = *(const half8*)(A + (size_t)(bm + srow) * K + k0 + spart * 8);
    *(half8*)&bs[srow][spart * 8] = *(const half8*)(B + (size_t)(bn + srow) * K + k0 + spart * 8);
    __syncthreads();
    half8 af = *(const half8*)&as[w * 16 + m15][q * 8];
#pragma unroll
    for (int ns = 0; ns < 4; ++ns) {
      half8 bf = *(const half8*)&bs[ns * 16 + m15][q * 8];
      acc[ns] = __builtin_amdgcn_mfma_f32_16x16x32_f16(af, bf, acc[ns], 0, 0, 0);
    }
  }
#pragma unroll
  for (int ns = 0; ns < 4; ++ns) {
    int gn = bn + ns * 16 + m15;
    float bv = hasbias ? bias[gn] : 0.f;
#pragma unroll
    for (int r = 0; r < 4; ++r) {
      int gm = bm + w * 16 + q * 4 + r;
      float v = acc[ns][r] + bv;
      if (do_relu) v = fmaxf(v, 0.f);
      if (f16out) ((_Float16*)Cout)[(size_t)gm * N + gn] = (_Float16)v;
      else ((float*)Cout)[(size_t)gm * N + gn] = v;
    }
  }
}

// ---------------- recurrent layer: 4 blocks = (dir x half), 512 threads ----------------
// Block (d, mh) owns units [mh*128, mh*128+128): M-tiles mh*32 .. mh*32+31; wave w holds
// 4 tiles x 8 kc = 32 named half8 (128 regs, unified-file resident; R5 proved 64 fit at
// VGPR_Count=56, demand here ~200 of 256). Exactly ONE partner block per block; its 4
// updater waves each publish one contiguous 256 B tagged store, and our 4 reader waves
// map 1:1 onto those stores -> publish visibility is wave-aligned, killing R5's
// slowest-of-3-publishers poll tail. Exchange via RELAXED agent-scope atomics only
// (no fences, no dual-publish — R6's regression). Parity double-buffer as before.
#define MFMAF(Wf, Bf, Acc) __builtin_amdgcn_mfma_f32_16x16x32_f16((Wf), (Bf), (Acc), 0, 0, 0)
__global__ __launch_bounds__(512, 1) void lstm_layer(
    const half8* __restrict__ wgt,   // this layer's packed Whh (pre-offset)
    const float* __restrict__ P,     // [2 dir][4096 row][1024 jp]  (jp = u*4 + gate)
    _Float16* __restrict__ Hout,     // [4096][512]  (row = n*2048+t, col = d*256+u)
    unsigned* __restrict__ xg,       // [2 par][2 d][2 mh][256] tagged words
    int tagbase) {                   // layer-unique tag offset (never 0xAAAA)
  const int d = blockIdx.x >> 1, mh = blockIdx.x & 1;
  __shared__ _Float16 hbuf[2 * 2 * 288];            // [buf][chain][288] (288: bank split)
  __shared__ float4 gbuf[2 * 128];                  // [chain][unit_local]
  const int tid = threadIdx.x;
  const int w = tid >> 6, lane = tid & 63;
  const int q = lane >> 4, m15 = lane & 15, n2 = m15 & 1;
  // updater role (waves 0-3): cell c_idx = tid: chain = tid>>7, unit_local = tid&127
  const int uchain = (tid >> 7) & 1, ul = tid & 127;
  const int ug = mh * 128 + ul;                     // global unit for updaters
  // reader role (waves 4-7): word rr from the single partner (1-mh)
  const int rr = tid - 256;
  const int rchain = (rr >> 7) & 1, rul = rr & 127;

  const half8* wb = wgt + ((size_t)((d * 64 + mh * 32 + w * 4) * 8)) * 64 + lane;
#define WLD(ti, kc) wb[((ti) * 8 + (kc)) * 64]
  half8 WA0 = WLD(0, 0), WA1 = WLD(0, 1), WA2 = WLD(0, 2), WA3 = WLD(0, 3);
  half8 WA4 = WLD(0, 4), WA5 = WLD(0, 5), WA6 = WLD(0, 6), WA7 = WLD(0, 7);
  half8 WB0 = WLD(1, 0), WB1 = WLD(1, 1), WB2 = WLD(1, 2), WB3 = WLD(1, 3);
  half8 WB4 = WLD(1, 4), WB5 = WLD(1, 5), WB6 = WLD(1, 6), WB7 = WLD(1, 7);
  half8 WC0 = WLD(2, 0), WC1 = WLD(2, 1), WC2 = WLD(2, 2), WC3 = WLD(2, 3);
  half8 WC4 = WLD(2, 4), WC5 = WLD(2, 5), WC6 = WLD(2, 6), WC7 = WLD(2, 7);
  half8 WD0 = WLD(3, 0), WD1 = WLD(3, 1), WD2 = WLD(3, 2), WD3 = WLD(3, 3);
  half8 WD4 = WLD(3, 4), WD5 = WLD(3, 5), WD6 = WLD(3, 6), WD7 = WLD(3, 7);
  for (int i = tid; i < 1152; i += 512) hbuf[i] = (_Float16)0.f;
  float c = 0.f;
  float4 pv;
  if (w < 4)   // prefetch step-0 input part
    pv = *(const float4*)(P + ((size_t)(d * 4096 + uchain * 2048 + (d ? 2047 : 0))) * 1024 + ug * 4);
  __syncthreads();

  for (int s = 0; s < 2048; ++s) {
    const int t = d ? (2047 - s) : s;
    const int cur = s & 1, nxt = cur ^ 1, par = (s + 1) & 1;
    float4 pv_next;
    if (w < 4 && s < 2047) {  // prefetch NEXT step's input part (hidden under this step)
      const int tn = d ? (t - 1) : (t + 1);
      pv_next = *(const float4*)(P + ((size_t)(d * 4096 + uchain * 2048 + tn)) * 1024 + ug * 4);
    }
    const _Float16* hb = hbuf + (cur * 2 + n2) * 288 + q * 8;
    f32x4 acc0 = {}, acc1 = {}, acc2 = {}, acc3 = {};
#define STEPKC(kc) { half8 bf = *(const half8*)(hb + (kc) * 32);  \
    acc0 = MFMAF(WA##kc, bf, acc0); acc1 = MFMAF(WB##kc, bf, acc1); \
    acc2 = MFMAF(WC##kc, bf, acc2); acc3 = MFMAF(WD##kc, bf, acc3); }
    STEPKC(0) STEPKC(1) STEPKC(2) STEPKC(3) STEPKC(4) STEPKC(5) STEPKC(6) STEPKC(7)
    if (m15 < 2) {   // task lanes: accN holds 4 gates of local unit (w*4+N)*4+q, chain m15
      gbuf[m15 * 128 + (w * 4 + 0) * 4 + q] = make_float4(acc0[0], acc0[1], acc0[2], acc0[3]);
      gbuf[m15 * 128 + (w * 4 + 1) * 4 + q] = make_float4(acc1[0], acc1[1], acc1[2], acc1[3]);
      gbuf[m15 * 128 + (w * 4 + 2) * 4 + q] = make_float4(acc2[0], acc2[1], acc2[2], acc2[3]);
      gbuf[m15 * 128 + (w * 4 + 3) * 4 + q] = make_float4(acc3[0], acc3[1], acc3[2], acc3[3]);
    }
    __syncthreads();
    const unsigned tag = (unsigned)(tagbase + s + 1);
    if (w < 4) {     // updaters: one (chain, unit) cell each, c persistent in-register
      float4 g = gbuf[uchain * 128 + ul];
      float xi = g.x + pv.x, xf = g.y + pv.y, xgg = g.z + pv.z, xo = g.w + pv.w;
      float cn = sigf(xf) * c + sigf(xi) * tanhf_(xgg);
      c = cn;
      float h = sigf(xo) * tanhf_(cn);
      _Float16 h16 = (_Float16)h;
      Hout[(size_t)(uchain * 2048 + t) * 512 + d * 256 + ug] = h16;
      if (s < 2047) {
        hbuf[(nxt * 2 + uchain) * 288 + ug] = h16;
        unsigned word = (tag << 16) | (unsigned)__builtin_bit_cast(unsigned short, h16);
        __hip_atomic_store(&xg[((par * 2 + d) * 2 + mh) * 256 + tid], word,
                           __ATOMIC_RELAXED, AGENT);
      }
    } else if (s < 2047) {  // readers: spin on one remote tagged word from the single partner
      unsigned* src = &xg[((par * 2 + d) * 2 + (1 - mh)) * 256 + rr];
      unsigned word = __hip_atomic_load(src, __ATOMIC_RELAXED, AGENT);
      while ((word >> 16) != tag) word = __hip_atomic_load(src, __ATOMIC_RELAXED, AGENT);
      hbuf[(nxt * 2 + rchain) * 288 + (1 - mh) * 128 + rul] =
          __builtin_bit_cast(_Float16, (unsigned short)(word & 0xffffu));
    }
    if (w < 4) pv = pv_next;
    __syncthreads();
  }
}

// ---------------- pair scorer: one wave per pair ----------------
__global__ __launch_bounds__(256) void pair_kernel(
    const float* __restrict__ S, const int* __restrict__ pair_r, const int* __restrict__ pair_l,
    const float* __restrict__ b3, const float* __restrict__ Wout, const float* __restrict__ bout,
    float* __restrict__ out) {
  const int wid = blockIdx.x * 4 + (threadIdx.x >> 6);
  const int lane = threadIdx.x & 63;
  const int r = pair_r[wid], l = pair_l[wid];
  const float* sr = S + (size_t)r * 1024;
  const float* sl = S + (size_t)(2048 + l) * 1024;
  float a0 = 0.f, a1 = 0.f;
#pragma unroll
  for (int cch = 0; cch < 4; ++cch) {
    int j = cch * 256 + lane * 4;
    float4 vr = *(const float4*)(sr + j);
    float4 vl = *(const float4*)(sl + j);
    float4 bb = *(const float4*)(b3 + j);
    float4 w0 = *(const float4*)(Wout + j);
    float4 w1 = *(const float4*)(Wout + 1024 + j);
    float v;
    v = fmaxf(0.f, 0.5f * (vr.x + vl.x) + bb.x); a0 += v * w0.x; a1 += v * w1.x;
    v = fmaxf(0.f, 0.5f * (vr.y + vl.y) + bb.y); a0 += v * w0.y; a1 += v * w1.y;
    v = fmaxf(0.f, 0.5f * (vr.z + vl.z) + bb.z); a0 += v * w0.z; a1 += v * w1.z;
    v = fmaxf(0.f, 0.5f * (vr.w + vl.w) + bb.w); a0 += v * w0.w; a1 += v * w1.w;
  }
#pragma unroll
  for (int off = 32; off; off >>= 1) {
    a0 += __shfl_xor(a0, off, 64);
    a1 += __shfl_xor(a1, off, 64);
  }
  if (lane == 0) {
    float l0 = a0 + bout[0], l1 = a1 + bout[1];
    float m = fmaxf(l0, l1);
    float lse = m + logf(__expf(l0 - m) + __expf(l1 - m));
    out[(size_t)wid * 2] = l0 - lse;
    out[(size_t)wid * 2 + 1] = l1 - lse;
  }
}

extern "C" void kernel_launch(void* const* d_in, const int* in_sizes, int n_in,
                              void* d_out, int out_size, void* d_ws, size_t ws_size,
                              hipStream_t stream) {
  (void)in_sizes; (void)n_in; (void)out_size;
  const float* v_r  = (const float*)d_in[0];
  const float* v_l  = (const float*)d_in[1];
  const int* pair_r = (const int*)d_in[2];
  const int* pair_l = (const int*)d_in[3];
  const float* Wih0 = (const float*)d_in[4];
  const float* Whh0 = (const float*)d_in[5];
  const float* bih0 = (const float*)d_in[6];
  const float* bhh0 = (const float*)d_in[7];
  const float* Wih1 = (const float*)d_in[8];
  const float* Whh1 = (const float*)d_in[9];
  const float* bih1 = (const float*)d_in[10];
  const float* bhh1 = (const float*)d_in[11];
  const float* W1   = (const float*)d_in[12];
  const float* b1   = (const float*)d_in[13];
  const float* W2   = (const float*)d_in[14];
  const float* b2   = (const float*)d_in[15];
  const float* W3   = (const float*)d_in[16];
  const float* b3   = (const float*)d_in[17];
  const float* Wout = (const float*)d_in[18];
  const float* bout = (const float*)d_in[19];

  if (ws_size < WS_NEED) return;
  char* ws = (char*)d_ws;
  half8* wgt      = (half8*)(ws + O_WGT);
  _Float16* xf16  = (_Float16*)(ws + O_XF16);
  _Float16* wih0p = (_Float16*)(ws + O_WIH0P);
  float* b0p      = (float*)(ws + O_B0P);
  _Float16* wih1p = (_Float16*)(ws + O_WIH1P);
  float* b1p      = (float*)(ws + O_B1P);
  _Float16* w1f   = (_Float16*)(ws + O_W1F);
  _Float16* w2f   = (_Float16*)(ws + O_W2F);
  _Float16* w3sf  = (_Float16*)(ws + O_W3SF);
  float* p0       = (float*)(ws + O_P0);
  _Float16* h0    = (_Float16*)(ws + O_H0);
  float* p1       = (float*)(ws + O_P1);
  _Float16* h1    = (_Float16*)(ws + O_H1);
  _Float16* m1    = (_Float16*)(ws + O_M1);
  _Float16* e     = (_Float16*)(ws + O_E);
  float* sbuf     = (float*)(ws + O_S);
  unsigned* xg    = (unsigned*)(ws + O_XG);

  pack_whh<<<512, 256, 0, stream>>>(Whh0, Whh1, wgt);
  pack_misc<<<11024, 256, 0, stream>>>(v_r, v_l, Wih0, bih0, bhh0, Wih1, bih1, bhh1,
                                       W1, W2, W3, xf16, wih0p, b0p, wih1p, b1p, w1f, w2f, w3sf);
  // layer-0 input parts (both chains stacked as 4096 rows)
  gemm_nt<<<dim3(64, 16), 256, 0, stream>>>(xf16, wih0p, b0p, p0, 1024, 32, 0, 0, 1);
  gemm_nt<<<dim3(64, 16), 256, 0, stream>>>(xf16, wih0p + 32768, b0p + 1024,
                                            p0 + (size_t)4096 * 1024, 1024, 32, 0, 0, 1);
  lstm_layer<<<4, 512, 0, stream>>>(wgt, p0, h0, xg, 4096);
  // layer-1 input parts
  gemm_nt<<<dim3(64, 16), 256, 0, stream>>>(h0, wih1p, b1p, p1, 1024, 512, 0, 0, 1);
  gemm_nt<<<dim3(64, 16), 256, 0, stream>>>(h0, wih1p + 524288, b1p + 1024,
                                            p1 + (size_t)4096 * 1024, 1024, 512, 0, 0, 1);
  lstm_layer<<<4, 512, 0, stream>>>(wgt + 65536, p1, h1, xg, 8192);
  // MLP + symmetrized pair rep precompute
  gemm_nt<<<dim3(64, 16), 256, 0, stream>>>(h1, w1f, b1, m1, 1024, 512, 1, 1, 1);
  gemm_nt<<<dim3(64, 8), 256, 0, stream>>>(m1, w2f, b2, e, 512, 1024, 1, 1, 1);
  gemm_nt<<<dim3(64, 16), 256, 0, stream>>>(e, w3sf, nullptr, sbuf, 1024, 512, 0, 0, 0);
  pair_kernel<<<16384, 256, 0, stream>>>(sbuf, pair_r, pair_l, b3, Wout, bout, (float*)d_out);
}

// Round 8
// 6533.646 us; speedup vs baseline: 1.1311x; 1.1311x over previous
//
#include <hip/hip_runtime.h>

typedef _Float16 half8 __attribute__((ext_vector_type(8)));
typedef float f32x4 __attribute__((ext_vector_type(4)));

#define AGENT __HIP_MEMORY_SCOPE_AGENT

__device__ __forceinline__ float sigf(float x) { return 1.f / (1.f + __expf(-x)); }
__device__ __forceinline__ float tanhf_(float x) {
  float e = __expf(-2.f * fabsf(x));
  float t = (1.f - e) / (1.f + e);
  return copysignf(t, x);
}

// Barrier with LDS-only drain: s_barrier WITHOUT the compiler's vmcnt(0) — global
// stores (Hout, xg publish) must NOT be waited at the barrier (LLC ack ~600-900 cyc).
#define BAR_LGKM() asm volatile("s_waitcnt lgkmcnt(0)\ns_barrier" ::: "memory")

// ---------------- workspace layout (bytes) ----------------
static const size_t O_WGT   = 0;                                  // 2 MB packed Whh f16
static const size_t O_XF16  = O_WGT   + (size_t)2*1024*1024;      // 4096x32 f16
static const size_t O_WIH0P = O_XF16  + 262144;                   // 2x1024x32 f16 (rows permuted)
static const size_t O_B0P   = O_WIH0P + 131072;                   // 2x1024 f32 (permuted)
static const size_t O_WIH1P = O_B0P   + 8192;                     // 2x1024x512 f16 (permuted)
static const size_t O_B1P   = O_WIH1P + 2097152;                  // 2x1024 f32
static const size_t O_W1F   = O_B1P   + 8192;                     // 1024x512 f16
static const size_t O_W2F   = O_W1F   + 1048576;                  // 512x1024 f16
static const size_t O_W3SF  = O_W2F   + 1048576;                  // 1024x512 f16 (W3a+W3b)
static const size_t O_P0    = O_W3SF  + 1048576;                  // 2x4096x1024 f32
static const size_t O_H0    = O_P0    + (size_t)32*1024*1024;     // 4096x512 f16
static const size_t O_P1    = O_H0    + 4194304;                  // 2x4096x1024 f32
static const size_t O_H1    = O_P1    + (size_t)32*1024*1024;     // 4096x512 f16
static const size_t O_M1    = O_H1    + 4194304;                  // 4096x1024 f16
static const size_t O_E     = O_M1    + 8388608;                  // 4096x512 f16
static const size_t O_S     = O_E     + 4194304;                  // 4096x1024 f32
static const size_t O_XG    = O_S     + (size_t)16*1024*1024;     // 8 KB tagged h-exchange
static const size_t WS_NEED = O_XG    + 8192;

// ---------------- pack recurrent weights into per-lane MFMA A-fragments ----------------
// Layout: wgt[layer][d][mt 0..63][kc 0..7][lane 0..63] half8.
// M-tile mt covers permuted rows: row m in tile -> unit = mt*4 + (m>>2), gate = m&3,
// original row = gate*256 + unit. A-frag (16x16x32 f16): lane holds
// A[m=lane&15][k = kc*32 + (lane>>4)*8 + j], j=0..7.
__global__ void pack_whh(const float* __restrict__ Whh0, const float* __restrict__ Whh1,
                         half8* __restrict__ wgt) {
  int flat = blockIdx.x * 256 + threadIdx.x;        // [0, 131072)
  int lane = flat & 63;
  int kc   = (flat >> 6) & 7;
  int mt   = (flat >> 9) & 63;
  int d    = (flat >> 15) & 1;
  int layer = flat >> 16;
  int m = lane & 15, q = lane >> 4;
  int ul = mt * 4 + (m >> 2), gate = m & 3;
  int grow = gate * 256 + ul;
  const float* src = (layer ? Whh1 : Whh0) + ((size_t)d * 1024 + grow) * 256 + kc * 32 + q * 8;
  half8 v;
#pragma unroll
  for (int j = 0; j < 8; ++j) v[j] = (_Float16)src[j];
  wgt[flat] = v;
}

// ---------------- pack everything else ----------------
__global__ void pack_misc(const float* __restrict__ v_r, const float* __restrict__ v_l,
                          const float* __restrict__ Wih0, const float* __restrict__ bih0,
                          const float* __restrict__ bhh0, const float* __restrict__ Wih1,
                          const float* __restrict__ bih1, const float* __restrict__ bhh1,
                          const float* __restrict__ W1, const float* __restrict__ W2,
                          const float* __restrict__ W3,
                          _Float16* __restrict__ xf16, _Float16* __restrict__ wih0p,
                          float* __restrict__ b0p, _Float16* __restrict__ wih1p,
                          float* __restrict__ b1p, _Float16* __restrict__ w1f,
                          _Float16* __restrict__ w2f, _Float16* __restrict__ w3sf) {
  int idx = blockIdx.x * 256 + threadIdx.x;
  if (idx < 131072) {                               // X f16 [4096][32], K padded 22->32
    int row = idx >> 5, k = idx & 31;
    float v = 0.f;
    if (k < 22) v = (row < 2048) ? v_r[row * 22 + k] : v_l[(row - 2048) * 22 + k];
    xf16[idx] = (_Float16)v;
    return;
  }
  idx -= 131072;
  if (idx < 65536) {                                // Wih0 permuted rows, K padded
    int d = idx >> 15, jp = (idx >> 5) & 1023, k = idx & 31;
    int u = jp >> 2, g = jp & 3, j = g * 256 + u;
    float v = (k < 22) ? Wih0[((size_t)d * 1024 + j) * 22 + k] : 0.f;
    wih0p[idx] = (_Float16)v;
    return;
  }
  idx -= 65536;
  if (idx < 2048) {                                 // bias0 permuted
    int d = idx >> 10, jp = idx & 1023;
    int u = jp >> 2, g = jp & 3, j = d * 1024 + g * 256 + u;
    b0p[idx] = bih0[j] + bhh0[j];
    return;
  }
  idx -= 2048;
  if (idx < 1048576) {                              // Wih1 permuted rows
    int d = idx >> 19, jp = (idx >> 9) & 1023, k = idx & 511;
    int u = jp >> 2, g = jp & 3;
    wih1p[idx] = (_Float16)Wih1[((size_t)d * 1024 + g * 256 + u) * 512 + k];
    return;
  }
  idx -= 1048576;
  if (idx < 2048) {                                 // bias1 permuted
    int d = idx >> 10, jp = idx & 1023;
    int u = jp >> 2, g = jp & 3, j = d * 1024 + g * 256 + u;
    b1p[idx] = bih1[j] + bhh1[j];
    return;
  }
  idx -= 2048;
  if (idx < 524288) { w1f[idx] = (_Float16)W1[idx]; return; }
  idx -= 524288;
  if (idx < 524288) { w2f[idx] = (_Float16)W2[idx]; return; }
  idx -= 524288;
  if (idx < 524288) {                               // W3s = W3[:, :512] + W3[:, 512:]
    int j = idx >> 9, k = idx & 511;
    w3sf[idx] = (_Float16)(W3[(size_t)j * 1024 + k] + W3[(size_t)j * 1024 + 512 + k]);
    return;
  }
}

// ---------------- generic NT GEMM: C[M,N] = A[M,K]f16 * B[N,K]f16 (+bias)(+relu) ----------------
__global__ __launch_bounds__(256) void gemm_nt(
    const _Float16* __restrict__ A, const _Float16* __restrict__ B,
    const float* __restrict__ bias, void* __restrict__ Cout,
    int N, int K, int do_relu, int f16out, int hasbias) {
  __shared__ _Float16 as[64][40];
  __shared__ _Float16 bs[64][40];
  const int tid = threadIdx.x;
  const int w = tid >> 6, lane = tid & 63, q = lane >> 4, m15 = lane & 15;
  const int bm = blockIdx.x * 64, bn = blockIdx.y * 64;
  const int srow = tid >> 2, spart = tid & 3;
  f32x4 acc[4] = {};
  for (int k0 = 0; k0 < K; k0 += 32) {
    if (k0) __syncthreads();
    *(half8*)&as[srow][spart * 8] = *(const half8*)(A + (size_t)(bm + srow) * K + k0 + spart * 8);
    *(half8*)&bs[srow][spart * 8] = *(const half8*)(B + (size_t)(bn + srow) * K + k0 + spart * 8);
    __syncthreads();
    half8 af = *(const half8*)&as[w * 16 + m15][q * 8];
#pragma unroll
    for (int ns = 0; ns < 4; ++ns) {
      half8 bf = *(const half8*)&bs[ns * 16 + m15][q * 8];
      acc[ns] = __builtin_amdgcn_mfma_f32_16x16x32_f16(af, bf, acc[ns], 0, 0, 0);
    }
  }
#pragma unroll
  for (int ns = 0; ns < 4; ++ns) {
    int gn = bn + ns * 16 + m15;
    float bv = hasbias ? bias[gn] : 0.f;
#pragma unroll
    for (int r = 0; r < 4; ++r) {
      int gm = bm + w * 16 + q * 4 + r;
      float v = acc[ns][r] + bv;
      if (do_relu) v = fmaxf(v, 0.f);
      if (f16out) ((_Float16*)Cout)[(size_t)gm * N + gn] = (_Float16)v;
      else ((float*)Cout)[(size_t)gm * N + gn] = v;
    }
  }
}

// ---------------- recurrent layer: 8 blocks = (dir x quarter), 512 threads ----------------
// R5 topology (proven 3.07 ms) + two changes from the R6/R7 evidence:
//  (1) BAR_LGKM barriers — never drain vmcnt at the step barrier; the agent-scope
//      publish ack (~600-900 cyc at LLC) comes off the critical path. gbuf/hbuf are
//      LDS -> lgkmcnt(0) suffices. Hout has no in-kernel reader; xg is tag-validated.
//  (2) weight frags pinned live via empty asm (allocator was reloading them from L2
//      each iteration: VGPR_Count 56/92 << demand in R5/R7) so the reload traffic
//      doesn't become the floor once the stall shrinks. Demand ~107 <= 128: safe zone.
#define MFMAF(Wf, Bf, Acc) __builtin_amdgcn_mfma_f32_16x16x32_f16((Wf), (Bf), (Acc), 0, 0, 0)
__global__ __launch_bounds__(512, 1) void lstm_layer(
    const half8* __restrict__ wgt,   // this layer's packed Whh (pre-offset)
    const float* __restrict__ P,     // [2 dir][4096 row][1024 jp]  (jp = u*4 + gate)
    _Float16* __restrict__ Hout,     // [4096][512]  (row = n*2048+t, col = d*256+u)
    unsigned* __restrict__ xg,       // [2 par][2 d][4 q][2 chain][64] tagged words
    int tagbase) {                   // layer-unique tag offset (never 0xAAAA)
  const int d = blockIdx.x >> 2, mq = blockIdx.x & 3;
  __shared__ _Float16 hbuf[2 * 2 * 288];            // [buf][chain][288] (288: bank split)
  __shared__ float4 gbuf[2 * 64];                   // [chain][unit_local]
  const int tid = threadIdx.x;
  const int w = tid >> 6, lane = tid & 63;
  const int q = lane >> 4, m15 = lane & 15, n2 = m15 & 1;
  // updater role (waves 0-1): chain = w, unit_local = lane
  const int ug = mq * 64 + lane;                    // global unit for updaters
  // reader role (waves 2-7): 384 lanes <-> 3 partners x 128 words
  const int rr = tid - 128;
  const int rp = rr >> 7, ridx = rr & 127;
  const int srcq = (mq + 1 + rp) & 3;
  const int rchain = ridx >> 6, rul = ridx & 63;

  const half8* wb = wgt + ((size_t)((d * 64 + mq * 16 + w * 2) * 8)) * 64 + lane;
#define WLD(ti, kc) wb[((ti) * 8 + (kc)) * 64]
  half8 WA0 = WLD(0, 0), WA1 = WLD(0, 1), WA2 = WLD(0, 2), WA3 = WLD(0, 3);
  half8 WA4 = WLD(0, 4), WA5 = WLD(0, 5), WA6 = WLD(0, 6), WA7 = WLD(0, 7);
  half8 WB0 = WLD(1, 0), WB1 = WLD(1, 1), WB2 = WLD(1, 2), WB3 = WLD(1, 3);
  half8 WB4 = WLD(1, 4), WB5 = WLD(1, 5), WB6 = WLD(1, 6), WB7 = WLD(1, 7);
  for (int i = tid; i < 1152; i += 512) hbuf[i] = (_Float16)0.f;
  float c = 0.f;
  float4 pv;
  if (w < 2)   // prefetch step-0 input part
    pv = *(const float4*)(P + ((size_t)(d * 4096 + w * 2048 + (d ? 2047 : 0))) * 1024 + ug * 4);
  __syncthreads();

  for (int s = 0; s < 2048; ++s) {
    // pin weight frags as loop-live register values: forbids per-iteration remat/reload
    asm volatile("" : "+v"(WA0), "+v"(WA1), "+v"(WA2), "+v"(WA3),
                      "+v"(WA4), "+v"(WA5), "+v"(WA6), "+v"(WA7),
                      "+v"(WB0), "+v"(WB1), "+v"(WB2), "+v"(WB3),
                      "+v"(WB4), "+v"(WB5), "+v"(WB6), "+v"(WB7));
    const int t = d ? (2047 - s) : s;
    const int cur = s & 1, nxt = cur ^ 1, par = (s + 1) & 1;
    float4 pv_next;
    if (w < 2 && s < 2047) {  // prefetch NEXT step's input part (hidden under this step)
      const int tn = d ? (t - 1) : (t + 1);
      pv_next = *(const float4*)(P + ((size_t)(d * 4096 + w * 2048 + tn)) * 1024 + ug * 4);
    }
    const _Float16* hb = hbuf + (cur * 2 + n2) * 288 + q * 8;
    f32x4 acc0 = {}, acc1 = {};
#define STEPKC(kc) { half8 bf = *(const half8*)(hb + (kc) * 32);  \
    acc0 = MFMAF(WA##kc, bf, acc0); acc1 = MFMAF(WB##kc, bf, acc1); }
    STEPKC(0) STEPKC(1) STEPKC(2) STEPKC(3) STEPKC(4) STEPKC(5) STEPKC(6) STEPKC(7)
    if (m15 < 2) {   // task lanes: accN holds 4 gates of unit (w*2+N)*4+q, chain m15
      gbuf[m15 * 64 + (w * 2 + 0) * 4 + q] = make_float4(acc0[0], acc0[1], acc0[2], acc0[3]);
      gbuf[m15 * 64 + (w * 2 + 1) * 4 + q] = make_float4(acc1[0], acc1[1], acc1[2], acc1[3]);
    }
    BAR_LGKM();
    const unsigned tag = (unsigned)(tagbase + s + 1);
    if (w < 2) {     // updaters: one (chain=w, unit=lane) cell each, c in-register
      float4 g = gbuf[w * 64 + lane];
      float xi = g.x + pv.x, xf = g.y + pv.y, xgg = g.z + pv.z, xo = g.w + pv.w;
      float cn = sigf(xf) * c + sigf(xi) * tanhf_(xgg);
      c = cn;
      float h = sigf(xo) * tanhf_(cn);
      _Float16 h16 = (_Float16)h;
      if (s < 2047) {   // publish FIRST so the store leads the queue toward the LLC
        unsigned word = (tag << 16) | (unsigned)__builtin_bit_cast(unsigned short, h16);
        __hip_atomic_store(&xg[(((par * 2 + d) * 4 + mq) * 2 + w) * 64 + lane], word,
                           __ATOMIC_RELAXED, AGENT);
        hbuf[(nxt * 2 + w) * 288 + ug] = h16;
      }
      Hout[(size_t)(w * 2048 + t) * 512 + d * 256 + ug] = h16;
    } else if (s < 2047) {  // readers: spin on one remote tagged word each
      unsigned* src = &xg[(((par * 2 + d) * 4 + srcq) * 2 + rchain) * 64 + rul];
      unsigned word = __hip_atomic_load(src, __ATOMIC_RELAXED, AGENT);
      while ((word >> 16) != tag) word = __hip_atomic_load(src, __ATOMIC_RELAXED, AGENT);
      hbuf[(nxt * 2 + rchain) * 288 + srcq * 64 + rul] =
          __builtin_bit_cast(_Float16, (unsigned short)(word & 0xffffu));
    }
    if (w < 2) pv = pv_next;
    BAR_LGKM();
  }
}

// ---------------- pair scorer: one wave per pair ----------------
__global__ __launch_bounds__(256) void pair_kernel(
    const float* __restrict__ S, const int* __restrict__ pair_r, const int* __restrict__ pair_l,
    const float* __restrict__ b3, const float* __restrict__ Wout, const float* __restrict__ bout,
    float* __restrict__ out) {
  const int wid = blockIdx.x * 4 + (threadIdx.x >> 6);
  const int lane = threadIdx.x & 63;
  const int r = pair_r[wid], l = pair_l[wid];
  const float* sr = S + (size_t)r * 1024;
  const float* sl = S + (size_t)(2048 + l) * 1024;
  float a0 = 0.f, a1 = 0.f;
#pragma unroll
  for (int cch = 0; cch < 4; ++cch) {
    int j = cch * 256 + lane * 4;
    float4 vr = *(const float4*)(sr + j);
    float4 vl = *(const float4*)(sl + j);
    float4 bb = *(const float4*)(b3 + j);
    float4 w0 = *(const float4*)(Wout + j);
    float4 w1 = *(const float4*)(Wout + 1024 + j);
    float v;
    v = fmaxf(0.f, 0.5f * (vr.x + vl.x) + bb.x); a0 += v * w0.x; a1 += v * w1.x;
    v = fmaxf(0.f, 0.5f * (vr.y + vl.y) + bb.y); a0 += v * w0.y; a1 += v * w1.y;
    v = fmaxf(0.f, 0.5f * (vr.z + vl.z) + bb.z); a0 += v * w0.z; a1 += v * w1.z;
    v = fmaxf(0.f, 0.5f * (vr.w + vl.w) + bb.w); a0 += v * w0.w; a1 += v * w1.w;
  }
#pragma unroll
  for (int off = 32; off; off >>= 1) {
    a0 += __shfl_xor(a0, off, 64);
    a1 += __shfl_xor(a1, off, 64);
  }
  if (lane == 0) {
    float l0 = a0 + bout[0], l1 = a1 + bout[1];
    float m = fmaxf(l0, l1);
    float lse = m + logf(__expf(l0 - m) + __expf(l1 - m));
    out[(size_t)wid * 2] = l0 - lse;
    out[(size_t)wid * 2 + 1] = l1 - lse;
  }
}

extern "C" void kernel_launch(void* const* d_in, const int* in_sizes, int n_in,
                              void* d_out, int out_size, void* d_ws, size_t ws_size,
                              hipStream_t stream) {
  (void)in_sizes; (void)n_in; (void)out_size;
  const float* v_r  = (const float*)d_in[0];
  const float* v_l  = (const float*)d_in[1];
  const int* pair_r = (const int*)d_in[2];
  const int* pair_l = (const int*)d_in[3];
  const float* Wih0 = (const float*)d_in[4];
  const float* Whh0 = (const float*)d_in[5];
  const float* bih0 = (const float*)d_in[6];
  const float* bhh0 = (const float*)d_in[7];
  const float* Wih1 = (const float*)d_in[8];
  const float* Whh1 = (const float*)d_in[9];
  const float* bih1 = (const float*)d_in[10];
  const float* bhh1 = (const float*)d_in[11];
  const float* W1   = (const float*)d_in[12];
  const float* b1   = (const float*)d_in[13];
  const float* W2   = (const float*)d_in[14];
  const float* b2   = (const float*)d_in[15];
  const float* W3   = (const float*)d_in[16];
  const float* b3   = (const float*)d_in[17];
  const float* Wout = (const float*)d_in[18];
  const float* bout = (const float*)d_in[19];

  if (ws_size < WS_NEED) return;
  char* ws = (char*)d_ws;
  half8* wgt      = (half8*)(ws + O_WGT);
  _Float16* xf16  = (_Float16*)(ws + O_XF16);
  _Float16* wih0p = (_Float16*)(ws + O_WIH0P);
  float* b0p      = (float*)(ws + O_B0P);
  _Float16* wih1p = (_Float16*)(ws + O_WIH1P);
  float* b1p      = (float*)(ws + O_B1P);
  _Float16* w1f   = (_Float16*)(ws + O_W1F);
  _Float16* w2f   = (_Float16*)(ws + O_W2F);
  _Float16* w3sf  = (_Float16*)(ws + O_W3SF);
  float* p0       = (float*)(ws + O_P0);
  _Float16* h0    = (_Float16*)(ws + O_H0);
  float* p1       = (float*)(ws + O_P1);
  _Float16* h1    = (_Float16*)(ws + O_H1);
  _Float16* m1    = (_Float16*)(ws + O_M1);
  _Float16* e     = (_Float16*)(ws + O_E);
  float* sbuf     = (float*)(ws + O_S);
  unsigned* xg    = (unsigned*)(ws + O_XG);

  pack_whh<<<512, 256, 0, stream>>>(Whh0, Whh1, wgt);
  pack_misc<<<11024, 256, 0, stream>>>(v_r, v_l, Wih0, bih0, bhh0, Wih1, bih1, bhh1,
                                       W1, W2, W3, xf16, wih0p, b0p, wih1p, b1p, w1f, w2f, w3sf);
  // layer-0 input parts (both chains stacked as 4096 rows)
  gemm_nt<<<dim3(64, 16), 256, 0, stream>>>(xf16, wih0p, b0p, p0, 1024, 32, 0, 0, 1);
  gemm_nt<<<dim3(64, 16), 256, 0, stream>>>(xf16, wih0p + 32768, b0p + 1024,
                                            p0 + (size_t)4096 * 1024, 1024, 32, 0, 0, 1);
  lstm_layer<<<8, 512, 0, stream>>>(wgt, p0, h0, xg, 4096);
  // layer-1 input parts
  gemm_nt<<<dim3(64, 16), 256, 0, stream>>>(h0, wih1p, b1p, p1, 1024, 512, 0, 0, 1);
  gemm_nt<<<dim3(64, 16), 256, 0, stream>>>(h0, wih1p + 524288, b1p + 1024,
                                            p1 + (size_t)4096 * 1024, 1024, 512, 0, 0, 1);
  lstm_layer<<<8, 512, 0, stream>>>(wgt + 65536, p1, h1, xg, 8192);
  // MLP + symmetrized pair rep precompute
  gemm_nt<<<dim3(64, 16), 256, 0, stream>>>(h1, w1f, b1, m1, 1024, 512, 1, 1, 1);
  gemm_nt<<<dim3(64, 8), 256, 0, stream>>>(m1, w2f, b2, e, 512, 1024, 1, 1, 1);
  gemm_nt<<<dim3(64, 16), 256, 0, stream>>>(e, w3sf, nullptr, sbuf, 1024, 512, 0, 0, 0);
  pair_kernel<<<16384, 256, 0, stream>>>(sbuf, pair_r, pair_l, b3, Wout, bout, (float*)d_out);
}